// Round 7
// baseline (109.451 us; speedup 1.0000x reference)
//
#include <hip/hip_runtime.h>
#include <math.h>

#define Bp 256
#define Tp 128
#define SDp 8
#define ADp 2
#define Hp 3
#define Kp 4
#define HIDp 256
#define QDp (SDp + ADp)       // 10
#define X1Dp (Hp * Kp + QDp)  // 22  (row padded to 32 bf16 = 64 B)
#define QKLD 17               // qk row stride (floats)
#define POSB 16               // positions per block
#define LOG2E 1.4426950408889634f

typedef short bf16x8 __attribute__((ext_vector_type(8)));
typedef float f32x4  __attribute__((ext_vector_type(4)));

__device__ __forceinline__ unsigned short f2bf(float f) {
    unsigned u = __float_as_uint(f);
    unsigned r = (u + 0x7FFFu + ((u >> 16) & 1u)) >> 16;
    return (unsigned short)r;
}

// h1 LDS: row stride 512 B, XOR bits 4-6 with row&7 -> conflict-free b128 col reads
__device__ __forceinline__ unsigned h1_byte(int row, int colbytes) {
    return (((unsigned)row << 9) + (unsigned)colbytes) ^ ((unsigned)(row & 7) << 4);
}
// X1s LDS: row stride 64 B, XOR byte 4-5 with row bits 1-2 -> conflict-free b128 A reads
__device__ __forceinline__ unsigned x1_byte(int row, int colbytes) {
    return ((unsigned)row << 6) + ((unsigned)colbytes ^ (((unsigned)row & 6u) << 3));
}

// ---------------------------------------------------------------------------
// prep: one-time W1/W2 f32 -> bf16 (96 blocks).
// ---------------------------------------------------------------------------
__global__ __launch_bounds__(256) void prep_kernel(
    const float* __restrict__ W1, const float* __restrict__ W2,
    unsigned short* __restrict__ W1b, unsigned short* __restrict__ W2b)
{
    const int bid = blockIdx.x;
    const int tid = threadIdx.x;
    if (bid < 64) {                       // W2 -> bf16 (65536 elems)
        const int i = bid * 1024 + tid * 4;
        const float4 v = *(const float4*)(W2 + i);
        ushort4 o;
        o.x = f2bf(v.x); o.y = f2bf(v.y); o.z = f2bf(v.z); o.w = f2bf(v.w);
        *(ushort4*)(W2b + i) = o;
    } else {                              // W1 -> bf16, 32-col padded rows
        const int i = (bid - 64) * 256 + tid;   // 0..8191
        const int r = i >> 5, c = i & 31;
        W1b[i] = (c < X1Dp) ? f2bf(W1[r * X1Dp + c]) : (unsigned short)0;
    }
}

// ---------------------------------------------------------------------------
// main (fused): 2048 blocks x 256 threads (4 waves), 16 positions/block.
// Grid/CU = 8 > resident 4 -> second round of blocks pipelines behind the
// first (phase-A VALU of round 2 overlaps phase-C MFMA/L2 of round 1).
// LDS ~16 KB. VGPR target ~110 under __launch_bounds__(256,4).
//  - phase S: s4 || qkp precompute (16 t, global reads) || wv; b1/b2/Wout->LDS.
//  - Bf0 (W2b cols for i=0) issued BEFORE phase A: first C-group L2 latency
//    hides under the j-loop.
//  - phase A: jo = tid&15 covers 8 j's (rotated banks); shfl_xor(1,2,4,8);
//    no max-shift, j==t post-subtracted at finalize; X1 row -> swizzled LDS.
//  - phase B: one 16-row MFMA tile; wave owns 64 cols (4 n-tiles), all 4
//    B-frags preloaded; h1 -> swizzled LDS.
//  - phase C: A8[8] hoisted ONCE (loop-invariant, 16 rows); per i: Bf[8]
//    (i=0 pre-issued), two independent 4-MFMA acc chains; relu+Wout;
//    shfl_xor(1..8) reduce; partial[] combine; out.
// ---------------------------------------------------------------------------
__global__ __launch_bounds__(256, 4) void main_kernel(
    const float* __restrict__ state, const float* __restrict__ action,
    const float* __restrict__ Wk, const float* __restrict__ Wq,
    const float* __restrict__ Wv,
    const unsigned short* __restrict__ W1b, const unsigned short* __restrict__ W2b,
    const float* __restrict__ b1, const float* __restrict__ b2,
    const float* __restrict__ Wout, const float* __restrict__ bout,
    float* __restrict__ out)
{
    const int bid   = blockIdx.x;
    const int batch = bid >> 3;
    const int t0    = (bid & 7) * POSB;
    const int tid   = threadIdx.x;
    const int lane  = tid & 63;
    const int wave  = tid >> 6;     // 0..3
    const int quad  = lane >> 4;
    const int l16   = lane & 15;
    const int t_loc = tid >> 4;     // 0..15
    const int jo    = tid & 15;     // 16-way j split
    const int t     = t0 + t_loc;

    __shared__ float4 s4[Tp];                                 // 2 KB (full batch)
    __shared__ float  wv[Hp * Kp * Kp];                       // 192 B
    __shared__ float  qk[POSB * QKLD];                        // 1.1 KB
    __shared__ float  b1s[HIDp];                              // 1 KB
    __shared__ float  b2s[HIDp];                              // 1 KB
    __shared__ float  wouts[HIDp];                            // 1 KB
    __shared__ __align__(16) unsigned short X1s[POSB * 32];   // 1 KB (swizzled)
    __shared__ __align__(16) unsigned short h1s[POSB * 256];  // 8 KB (swizzled)
    __shared__ float partial[4][POSB];                        // 256 B

    // ---- phase S: parallel staging + per-t precompute ----
    if (tid < Tp) {
        s4[tid] = ((const float4*)(state + (size_t)batch * Tp * SDp))[tid * 2];
    } else if (tid < Tp + POSB) {
        const int ta = tid - Tp;            // 0..15
        const int tt = t0 + ta;
        float qs[QDp];
        {
            const float* srow = state + ((size_t)batch * Tp + tt) * SDp;
            const float4 v0 = *(const float4*)srow;
            const float4 v1 = *(const float4*)(srow + 4);
            qs[0]=v0.x; qs[1]=v0.y; qs[2]=v0.z; qs[3]=v0.w;
            qs[4]=v1.x; qs[5]=v1.y; qs[6]=v1.z; qs[7]=v1.w;
            const float* arow = action + ((size_t)batch * Tp + tt) * ADp;
            qs[8] = arow[0]; qs[9] = arow[1];
        }
        float q[Hp * Kp];
        #pragma unroll
        for (int r = 0; r < Hp * Kp; ++r) {
            float a = 0.f;
            #pragma unroll
            for (int d = 0; d < QDp; ++d) a += qs[d] * Wq[r * QDp + d];
            q[r] = a;
        }
        float* qrow = &qk[ta * QKLD];
        #pragma unroll
        for (int h = 0; h < Hp; ++h)
            #pragma unroll
            for (int c = 0; c < Kp; ++c) {
                float a = 0.f;
                #pragma unroll
                for (int k = 0; k < Kp; ++k) a += q[h * Kp + k] * Wk[(h * Kp + k) * Kp + c];
                qrow[h * 4 + c] = 0.5f * LOG2E * a;   // exp->exp2 fold; no max-shift
            }
        #pragma unroll
        for (int i = 0; i < 5; ++i) {
            const unsigned u = (unsigned)f2bf(qs[2*i]) | ((unsigned)f2bf(qs[2*i+1]) << 16);
            qrow[12 + i] = __uint_as_float(u);
        }
    } else if (tid < Tp + POSB + Hp * Kp * Kp) {
        wv[tid - Tp - POSB] = Wv[tid - Tp - POSB];
    }
    b1s[tid]   = b1[tid];
    b2s[tid]   = b2[tid];
    wouts[tid] = Wout[tid];

    // ---- pre-issue W2b B-frags for phase-C i=0 (hides L2 under phase A) ----
    bf16x8 Bf0[8];
    {
        const int col0 = (wave * 4 + 0) * 16 + l16;
        const unsigned short* wr0 = W2b + (size_t)col0 * HIDp + quad * 8;
        #pragma unroll
        for (int ks = 0; ks < 8; ++ks)
            Bf0[ks] = *(const bf16x8*)(wr0 + ks * 32);
    }
    __syncthreads();

    // ---- phase A: j-loop (all 256 threads; 8 j's each) ----
    float rq[12];
    #pragma unroll
    for (int i = 0; i < 3; ++i)
        *(float4*)&rq[i * 4] = *(const float4*)&qk[t_loc * QKLD + i * 4];

    float l[Hp] = {0.f, 0.f, 0.f};
    float ac[Hp][4] = {};
    #pragma unroll
    for (int i = 0; i < 8; ++i) {
        const int j = (jo << 3) | ((i + jo) & 7);   // rotated: 2-way banks (free)
        const float4 sj = s4[j];
        #pragma unroll
        for (int h = 0; h < Hp; ++h) {
            const float d = sj.x * rq[h*4] + sj.y * rq[h*4+1]
                          + sj.z * rq[h*4+2] + sj.w * rq[h*4+3];
            const float e = __builtin_amdgcn_exp2f(d);   // no j==t branch
            l[h] += e;
            ac[h][0] += e * sj.x; ac[h][1] += e * sj.y;
            ac[h][2] += e * sj.z; ac[h][3] += e * sj.w;
        }
    }
    #pragma unroll
    for (int off = 1; off < 16; off <<= 1) {
        #pragma unroll
        for (int h = 0; h < Hp; ++h) {
            l[h] += __shfl_xor(l[h], off);
            #pragma unroll
            for (int c = 0; c < Kp; ++c) ac[h][c] += __shfl_xor(ac[h][c], off);
        }
    }

    if (jo == 0) {
        const float4 st = s4[t];
        unsigned short rowb[32] __attribute__((aligned(16)));
        #pragma unroll
        for (int h = 0; h < Hp; ++h) {
            // remove the j==t term: e_tt = exp2(dot(qkp_h, s_t))
            const float dtt = st.x * rq[h*4] + st.y * rq[h*4+1]
                            + st.z * rq[h*4+2] + st.w * rq[h*4+3];
            const float ett = __builtin_amdgcn_exp2f(dtt);
            const float inv = 1.f / (l[h] - ett);
            const float rb0 = (ac[h][0] - ett * st.x) * inv - st.x;
            const float rb1 = (ac[h][1] - ett * st.y) * inv - st.y;
            const float rb2 = (ac[h][2] - ett * st.z) * inv - st.z;
            const float rb3 = (ac[h][3] - ett * st.w) * inv - st.w;
            #pragma unroll
            for (int k = 0; k < Kp; ++k) {
                const int r = h * Kp + k;
                rowb[r] = f2bf(rb0 * wv[r*4] + rb1 * wv[r*4+1] + rb2 * wv[r*4+2] + rb3 * wv[r*4+3]);
            }
        }
        #pragma unroll
        for (int i = 0; i < 5; ++i) {
            const unsigned u = __float_as_uint(qk[t_loc * QKLD + 12 + i]);
            rowb[12 + 2*i] = (unsigned short)(u & 0xffffu);
            rowb[13 + 2*i] = (unsigned short)(u >> 16);
        }
        #pragma unroll
        for (int i = X1Dp; i < 32; ++i) rowb[i] = 0;

        const uint4* srcv = (const uint4*)rowb;
        #pragma unroll
        for (int i = 0; i < 4; ++i)
            *(uint4*)((char*)X1s + x1_byte(t_loc, i * 16)) = srcv[i];
    }
    __syncthreads();

    // ---- phase B: MLP1, one 16-row tile; wave owns 64 cols (4 n-tiles) ----
    {
        bf16x8 bfr[4];                       // all B-frags in flight first
        #pragma unroll
        for (int n = 0; n < 4; ++n)
            bfr[n] = *(const bf16x8*)&W1b[(wave * 64 + n * 16 + l16) * 32 + quad * 8];
        const bf16x8 afr = *(const bf16x8*)((const char*)X1s + x1_byte(l16, quad * 16));
        #pragma unroll
        for (int n = 0; n < 4; ++n) {
            const int col = wave * 64 + n * 16 + l16;
            f32x4 acc = {0.f, 0.f, 0.f, 0.f};
            acc = __builtin_amdgcn_mfma_f32_16x16x32_bf16(afr, bfr[n], acc, 0, 0, 0);
            const float bb = b1s[col];
            #pragma unroll
            for (int r = 0; r < 4; ++r) {
                const int row = quad * 4 + r;
                *(unsigned short*)((char*)h1s + h1_byte(row, col * 2)) =
                    f2bf(fmaxf(acc[r] + bb, 0.f));
            }
        }
    }
    __syncthreads();

    // ---- phase C: MLP2 + out (wave owns cols [wave*64, wave*64+64)) ----
    bf16x8 A8[8];                            // loop-invariant: hoisted ONCE
    #pragma unroll
    for (int ks = 0; ks < 8; ++ks)
        A8[ks] = *(const bf16x8*)((const char*)h1s + h1_byte(l16, ks * 64 + quad * 16));

    float rsum[4] = {0.f, 0.f, 0.f, 0.f};
    #pragma unroll
    for (int i = 0; i < 4; ++i) {
        const int col = (wave * 4 + i) * 16 + l16;
        bf16x8 Bf[8];
        if (i == 0) {
            #pragma unroll
            for (int ks = 0; ks < 8; ++ks) Bf[ks] = Bf0[ks];
        } else {
            const unsigned short* wr = W2b + (size_t)col * HIDp + quad * 8;
            #pragma unroll
            for (int ks = 0; ks < 8; ++ks)
                Bf[ks] = *(const bf16x8*)(wr + ks * 32);
        }
        const float bb = b2s[col];
        const float wo = wouts[col];
        // two independent 4-long MFMA chains
        f32x4 acc0 = {0.f, 0.f, 0.f, 0.f};
        f32x4 acc1 = {0.f, 0.f, 0.f, 0.f};
        #pragma unroll
        for (int ks = 0; ks < 4; ++ks) {
            acc0 = __builtin_amdgcn_mfma_f32_16x16x32_bf16(A8[ks],     Bf[ks],     acc0, 0, 0, 0);
            acc1 = __builtin_amdgcn_mfma_f32_16x16x32_bf16(A8[ks + 4], Bf[ks + 4], acc1, 0, 0, 0);
        }
        #pragma unroll
        for (int r = 0; r < 4; ++r)
            rsum[r] += fmaxf(acc0[r] + acc1[r] + bb, 0.f) * wo;
    }

    #pragma unroll
    for (int off = 1; off < 16; off <<= 1)
        #pragma unroll
        for (int r = 0; r < 4; ++r)
            rsum[r] += __shfl_xor(rsum[r], off);

    if (l16 == 0) {
        #pragma unroll
        for (int r = 0; r < 4; ++r)
            partial[wave][quad * 4 + r] = rsum[r];
    }
    __syncthreads();

    if (tid < POSB) {
        out[(size_t)batch * Tp + t0 + tid] =
            partial[0][tid] + partial[1][tid] + partial[2][tid]
          + partial[3][tid] + bout[0];
    }
}

extern "C" void kernel_launch(void* const* d_in, const int* in_sizes, int n_in,
                              void* d_out, int out_size, void* d_ws, size_t ws_size,
                              hipStream_t stream) {
    const float* state  = (const float*)d_in[0];
    const float* action = (const float*)d_in[1];
    const float* Wk     = (const float*)d_in[2];
    const float* Wq     = (const float*)d_in[3];
    const float* Wv     = (const float*)d_in[4];
    const float* W1     = (const float*)d_in[5];
    const float* b1     = (const float*)d_in[6];
    const float* W2     = (const float*)d_in[7];
    const float* b2     = (const float*)d_in[8];
    const float* Wout   = (const float*)d_in[9];
    const float* bout   = (const float*)d_in[10];
    float* out = (float*)d_out;

    char* ws = (char*)d_ws;
    unsigned short* W1b = (unsigned short*)(ws);           // 16 KB
    unsigned short* W2b = (unsigned short*)(ws + 16384);   // 128 KB

    prep_kernel<<<96, 256, 0, stream>>>(W1, W2, W1b, W2b);
    main_kernel<<<8 * Bp, 256, 0, stream>>>(state, action, Wk, Wq, Wv,
                                            W1b, W2b, b1, b2, Wout, bout, out);
}

// Round 8
// 108.995 us; speedup vs baseline: 1.0042x; 1.0042x over previous
//
#include <hip/hip_runtime.h>
#include <math.h>

#define Bp 256
#define Tp 128
#define SDp 8
#define ADp 2
#define Hp 3
#define Kp 4
#define HIDp 256
#define QDp (SDp + ADp)       // 10
#define X1Dp (Hp * Kp + QDp)  // 22  (row padded to 32 bf16 = 64 B)
#define QKLD 17               // qk row stride (floats)
#define LOG2E 1.4426950408889634f

typedef short bf16x8 __attribute__((ext_vector_type(8)));
typedef float f32x4  __attribute__((ext_vector_type(4)));

__device__ __forceinline__ unsigned short f2bf(float f) {
    unsigned u = __float_as_uint(f);
    unsigned r = (u + 0x7FFFu + ((u >> 16) & 1u)) >> 16;
    return (unsigned short)r;
}

// h1 LDS: row stride 512 B, XOR bits 4-6 with row&7 -> conflict-free b128 col reads
__device__ __forceinline__ unsigned h1_byte(int row, int colbytes) {
    return (((unsigned)row << 9) + (unsigned)colbytes) ^ ((unsigned)(row & 7) << 4);
}
// X1s LDS: row stride 64 B, XOR byte 4-5 with row bits 1-2 -> conflict-free b128 A reads
__device__ __forceinline__ unsigned x1_byte(int row, int colbytes) {
    return ((unsigned)row << 6) + ((unsigned)colbytes ^ (((unsigned)row & 6u) << 3));
}

// ---------------------------------------------------------------------------
// prep: one-time W1/W2 f32 -> bf16 (96 blocks).
// ---------------------------------------------------------------------------
__global__ __launch_bounds__(256) void prep_kernel(
    const float* __restrict__ W1, const float* __restrict__ W2,
    unsigned short* __restrict__ W1b, unsigned short* __restrict__ W2b)
{
    const int bid = blockIdx.x;
    const int tid = threadIdx.x;
    if (bid < 64) {                       // W2 -> bf16 (65536 elems)
        const int i = bid * 1024 + tid * 4;
        const float4 v = *(const float4*)(W2 + i);
        ushort4 o;
        o.x = f2bf(v.x); o.y = f2bf(v.y); o.z = f2bf(v.z); o.w = f2bf(v.w);
        *(ushort4*)(W2b + i) = o;
    } else {                              // W1 -> bf16, 32-col padded rows
        const int i = (bid - 64) * 256 + tid;   // 0..8191
        const int r = i >> 5, c = i & 31;
        W1b[i] = (c < X1Dp) ? f2bf(W1[r * X1Dp + c]) : (unsigned short)0;
    }
}

// ---------------------------------------------------------------------------
// main (fused): 1024 blocks x 256 threads (4 waves), 32 positions/block
// (R6 structure — best measured). New in R8: phase-C is an 8-half-group
// depth-1 B-prefetch pipeline, and phase-B/C first loads are pre-issued
// BEFORE phase A so their L2 latency hides under the attention j-loop.
// ---------------------------------------------------------------------------
__global__ __launch_bounds__(256, 4) void main_kernel(
    const float* __restrict__ state, const float* __restrict__ action,
    const float* __restrict__ Wk, const float* __restrict__ Wq,
    const float* __restrict__ Wv,
    const unsigned short* __restrict__ W1b, const unsigned short* __restrict__ W2b,
    const float* __restrict__ b1, const float* __restrict__ b2,
    const float* __restrict__ Wout, const float* __restrict__ bout,
    float* __restrict__ out)
{
    const int bid   = blockIdx.x;
    const int batch = bid >> 2;
    const int t0    = (bid & 3) * 32;
    const int tid   = threadIdx.x;
    const int lane  = tid & 63;
    const int wave  = tid >> 6;     // 0..3
    const int quad  = lane >> 4;
    const int l16   = lane & 15;
    const int t_loc = tid >> 3;     // 0..31
    const int jo    = tid & 7;      // 8-way j split
    const int t     = t0 + t_loc;

    __shared__ float4 s4[Tp];                                // 2 KB
    __shared__ float  wv[Hp * Kp * Kp];                      // 192 B
    __shared__ float  qk[32 * QKLD];                         // 2.1 KB
    __shared__ float  b1s[HIDp];                             // 1 KB
    __shared__ float  b2s[HIDp];                             // 1 KB
    __shared__ float  wouts[HIDp];                           // 1 KB
    __shared__ __align__(16) unsigned short X1s[32 * 32];    // 2 KB (swizzled)
    __shared__ __align__(16) unsigned short h1s[32 * 256];   // 16 KB (swizzled)
    __shared__ float partial[4][32];                         // 512 B

    // ---- pre-issue phase-B (W1b) and phase-C group-0 (W2b) loads:
    //      in flight across phase S + phase A (~1500 cycles of cover) ----
    const int rt_b  = wave & 1;          // phase-B row-tile
    const int chh_b = wave >> 1;         // phase-B col-half
    bf16x8 bfr[8];
    #pragma unroll
    for (int n = 0; n < 8; ++n)
        bfr[n] = *(const bf16x8*)&W1b[(chh_b * 128 + n * 16 + l16) * 32 + quad * 8];
    bf16x8 Bc[4];
    {
        const unsigned short* wr0 = W2b + (size_t)((wave * 4 + 0) * 16 + l16) * HIDp + quad * 8;
        #pragma unroll
        for (int k = 0; k < 4; ++k)
            Bc[k] = *(const bf16x8*)(wr0 + k * 32);
    }

    // ---- phase S: parallel staging + per-t precompute ----
    if (tid < Tp) {
        s4[tid] = ((const float4*)(state + (size_t)batch * Tp * SDp))[tid * 2];
    } else if (tid < 160) {
        const int ta = tid - 128;           // 0..31
        const int tt = t0 + ta;
        float qs[QDp];
        {
            const float* srow = state + ((size_t)batch * Tp + tt) * SDp;
            const float4 v0 = *(const float4*)srow;
            const float4 v1 = *(const float4*)(srow + 4);
            qs[0]=v0.x; qs[1]=v0.y; qs[2]=v0.z; qs[3]=v0.w;
            qs[4]=v1.x; qs[5]=v1.y; qs[6]=v1.z; qs[7]=v1.w;
            const float* arow = action + ((size_t)batch * Tp + tt) * ADp;
            qs[8] = arow[0]; qs[9] = arow[1];
        }
        float q[Hp * Kp];
        #pragma unroll
        for (int r = 0; r < Hp * Kp; ++r) {
            float a = 0.f;
            #pragma unroll
            for (int d = 0; d < QDp; ++d) a += qs[d] * Wq[r * QDp + d];
            q[r] = a;
        }
        float* qrow = &qk[ta * QKLD];
        #pragma unroll
        for (int h = 0; h < Hp; ++h)
            #pragma unroll
            for (int c = 0; c < Kp; ++c) {
                float a = 0.f;
                #pragma unroll
                for (int k = 0; k < Kp; ++k) a += q[h * Kp + k] * Wk[(h * Kp + k) * Kp + c];
                qrow[h * 4 + c] = 0.5f * LOG2E * a;   // exp->exp2 fold; no max-shift
            }
        #pragma unroll
        for (int i = 0; i < 5; ++i) {
            const unsigned u = (unsigned)f2bf(qs[2*i]) | ((unsigned)f2bf(qs[2*i+1]) << 16);
            qrow[12 + i] = __uint_as_float(u);
        }
    } else if (tid < 160 + Hp * Kp * Kp) {
        wv[tid - 160] = Wv[tid - 160];
    }
    b1s[tid]   = b1[tid];
    b2s[tid]   = b2[tid];
    wouts[tid] = Wout[tid];
    __syncthreads();

    // ---- phase A: j-loop (all 256 threads; 16 j's each) ----
    float rq[12];
    #pragma unroll
    for (int i = 0; i < 3; ++i)
        *(float4*)&rq[i * 4] = *(const float4*)&qk[t_loc * QKLD + i * 4];

    float l[Hp] = {0.f, 0.f, 0.f};
    float ac[Hp][4] = {};
    #pragma unroll
    for (int i = 0; i < 16; ++i) {
        const int j = (jo << 4) | ((i + jo) & 15);   // rotated: conflict-free banks
        const float4 sj = s4[j];
        #pragma unroll
        for (int h = 0; h < Hp; ++h) {
            const float d = sj.x * rq[h*4] + sj.y * rq[h*4+1]
                          + sj.z * rq[h*4+2] + sj.w * rq[h*4+3];
            const float e = __builtin_amdgcn_exp2f(d);   // no j==t branch
            l[h] += e;
            ac[h][0] += e * sj.x; ac[h][1] += e * sj.y;
            ac[h][2] += e * sj.z; ac[h][3] += e * sj.w;
        }
    }
    #pragma unroll
    for (int off = 1; off < 8; off <<= 1) {
        #pragma unroll
        for (int h = 0; h < Hp; ++h) {
            l[h] += __shfl_xor(l[h], off);
            #pragma unroll
            for (int c = 0; c < Kp; ++c) ac[h][c] += __shfl_xor(ac[h][c], off);
        }
    }

    if (jo == 0) {
        const float4 st = s4[t];
        unsigned short rowb[32] __attribute__((aligned(16)));
        #pragma unroll
        for (int h = 0; h < Hp; ++h) {
            // remove the j==t term: e_tt = exp2(dot(qkp_h, s_t))
            const float dtt = st.x * rq[h*4] + st.y * rq[h*4+1]
                            + st.z * rq[h*4+2] + st.w * rq[h*4+3];
            const float ett = __builtin_amdgcn_exp2f(dtt);
            const float inv = 1.f / (l[h] - ett);
            const float rb0 = (ac[h][0] - ett * st.x) * inv - st.x;
            const float rb1 = (ac[h][1] - ett * st.y) * inv - st.y;
            const float rb2 = (ac[h][2] - ett * st.z) * inv - st.z;
            const float rb3 = (ac[h][3] - ett * st.w) * inv - st.w;
            #pragma unroll
            for (int k = 0; k < Kp; ++k) {
                const int r = h * Kp + k;
                rowb[r] = f2bf(rb0 * wv[r*4] + rb1 * wv[r*4+1] + rb2 * wv[r*4+2] + rb3 * wv[r*4+3]);
            }
        }
        #pragma unroll
        for (int i = 0; i < 5; ++i) {
            const unsigned u = __float_as_uint(qk[t_loc * QKLD + 12 + i]);
            rowb[12 + 2*i] = (unsigned short)(u & 0xffffu);
            rowb[13 + 2*i] = (unsigned short)(u >> 16);
        }
        #pragma unroll
        for (int i = X1Dp; i < 32; ++i) rowb[i] = 0;

        const uint4* srcv = (const uint4*)rowb;
        #pragma unroll
        for (int i = 0; i < 4; ++i)
            *(uint4*)((char*)X1s + x1_byte(t_loc, i * 16)) = srcv[i];
    }
    __syncthreads();

    // ---- phase B: MLP1 (wave -> row-tile rt_b, col-half chh_b); bfr pre-issued ----
    {
        const bf16x8 afr = *(const bf16x8*)((const char*)X1s +
                             x1_byte(rt_b * 16 + l16, quad * 16));
        #pragma unroll
        for (int n = 0; n < 8; ++n) {
            const int col = chh_b * 128 + n * 16 + l16;
            f32x4 acc = {0.f, 0.f, 0.f, 0.f};
            acc = __builtin_amdgcn_mfma_f32_16x16x32_bf16(afr, bfr[n], acc, 0, 0, 0);
            const float bb = b1s[col];
            #pragma unroll
            for (int r = 0; r < 4; ++r) {
                const int row = rt_b * 16 + quad * 4 + r;
                *(unsigned short*)((char*)h1s + h1_byte(row, col * 2)) =
                    f2bf(fmaxf(acc[r] + bb, 0.f));
            }
        }
    }
    __syncthreads();

    // ---- phase C: MLP2 + out; 8 half-groups (4 B-frags), depth-1 prefetch ----
    float rsum[2][4] = {};
    f32x4 acc0 = {0.f, 0.f, 0.f, 0.f};
    f32x4 acc1 = {0.f, 0.f, 0.f, 0.f};
    bf16x8 Bn[4];
    #pragma unroll
    for (int g = 0; g < 8; ++g) {
        const int i  = g >> 1;
        const int hf = g & 1;
        if (g < 7) {   // prefetch next half-group (in flight under MFMAs below)
            const int ni  = (g + 1) >> 1;
            const int nhf = (g + 1) & 1;
            const unsigned short* wr = W2b + (size_t)((wave * 4 + ni) * 16 + l16) * HIDp
                                     + nhf * 128 + quad * 8;
            #pragma unroll
            for (int k = 0; k < 4; ++k)
                Bn[k] = *(const bf16x8*)(wr + k * 32);
        }
        #pragma unroll
        for (int k = 0; k < 4; ++k) {
            const int ksg = hf * 4 + k;
            const bf16x8 a0 = *(const bf16x8*)((const char*)h1s +
                                h1_byte(l16,      ksg * 64 + quad * 16));
            const bf16x8 a1 = *(const bf16x8*)((const char*)h1s +
                                h1_byte(16 + l16, ksg * 64 + quad * 16));
            acc0 = __builtin_amdgcn_mfma_f32_16x16x32_bf16(a0, Bc[k], acc0, 0, 0, 0);
            acc1 = __builtin_amdgcn_mfma_f32_16x16x32_bf16(a1, Bc[k], acc1, 0, 0, 0);
        }
        if (hf == 1) {   // finalize column-group i
            const int col = (wave * 4 + i) * 16 + l16;
            const float bb = b2s[col];
            const float wo = wouts[col];
            #pragma unroll
            for (int r = 0; r < 4; ++r) {
                rsum[0][r] += fmaxf(acc0[r] + bb, 0.f) * wo;
                rsum[1][r] += fmaxf(acc1[r] + bb, 0.f) * wo;
            }
            acc0 = (f32x4){0.f, 0.f, 0.f, 0.f};
            acc1 = (f32x4){0.f, 0.f, 0.f, 0.f};
        }
        #pragma unroll
        for (int k = 0; k < 4; ++k) Bc[k] = Bn[k];   // SSA-renamed, no real movs
    }

    #pragma unroll
    for (int off = 1; off < 16; off <<= 1)
        #pragma unroll
        for (int rt = 0; rt < 2; ++rt)
            #pragma unroll
            for (int r = 0; r < 4; ++r)
                rsum[rt][r] += __shfl_xor(rsum[rt][r], off);

    if (l16 == 0) {
        #pragma unroll
        for (int rt = 0; rt < 2; ++rt)
            #pragma unroll
            for (int r = 0; r < 4; ++r)
                partial[wave][rt * 16 + quad * 4 + r] = rsum[rt][r];
    }
    __syncthreads();

    if (tid < 32) {
        out[(size_t)batch * Tp + t0 + tid] =
            partial[0][tid] + partial[1][tid] + partial[2][tid]
          + partial[3][tid] + bout[0];
    }
}

extern "C" void kernel_launch(void* const* d_in, const int* in_sizes, int n_in,
                              void* d_out, int out_size, void* d_ws, size_t ws_size,
                              hipStream_t stream) {
    const float* state  = (const float*)d_in[0];
    const float* action = (const float*)d_in[1];
    const float* Wk     = (const float*)d_in[2];
    const float* Wq     = (const float*)d_in[3];
    const float* Wv     = (const float*)d_in[4];
    const float* W1     = (const float*)d_in[5];
    const float* b1     = (const float*)d_in[6];
    const float* W2     = (const float*)d_in[7];
    const float* b2     = (const float*)d_in[8];
    const float* Wout   = (const float*)d_in[9];
    const float* bout   = (const float*)d_in[10];
    float* out = (float*)d_out;

    char* ws = (char*)d_ws;
    unsigned short* W1b = (unsigned short*)(ws);           // 16 KB
    unsigned short* W2b = (unsigned short*)(ws + 16384);   // 128 KB

    prep_kernel<<<96, 256, 0, stream>>>(W1, W2, W1b, W2b);
    main_kernel<<<4 * Bp, 256, 0, stream>>>(state, action, Wk, Wq, Wv,
                                            W1b, W2b, b1, b2, Wout, bout, out);
}

// Round 9
// 99.793 us; speedup vs baseline: 1.0968x; 1.0922x over previous
//
#include <hip/hip_runtime.h>
#include <math.h>

#define Bp 256
#define Tp 128
#define SDp 8
#define ADp 2
#define Hp 3
#define Kp 4
#define HIDp 256
#define QDp (SDp + ADp)       // 10
#define X1Dp (Hp * Kp + QDp)  // 22  (row padded to 32 bf16 = 64 B)
#define QKLD 17               // qk row stride (floats)
#define LOG2E 1.4426950408889634f

typedef short bf16x8 __attribute__((ext_vector_type(8)));
typedef float f32x4  __attribute__((ext_vector_type(4)));

__device__ __forceinline__ unsigned short f2bf(float f) {
    unsigned u = __float_as_uint(f);
    unsigned r = (u + 0x7FFFu + ((u >> 16) & 1u)) >> 16;
    return (unsigned short)r;
}

// h1 LDS: row stride 512 B, XOR bits 4-6 with row&7 -> conflict-free b128 col reads
__device__ __forceinline__ unsigned h1_byte(int row, int colbytes) {
    return (((unsigned)row << 9) + (unsigned)colbytes) ^ ((unsigned)(row & 7) << 4);
}
// X1s LDS: row stride 64 B, XOR byte 4-5 with row bits 1-2 -> conflict-free b128 A reads
__device__ __forceinline__ unsigned x1_byte(int row, int colbytes) {
    return ((unsigned)row << 6) + ((unsigned)colbytes ^ (((unsigned)row & 6u) << 3));
}

// ---------------------------------------------------------------------------
// prep: one-time W1/W2 f32 -> bf16 (96 blocks).
// ---------------------------------------------------------------------------
__global__ __launch_bounds__(256) void prep_kernel(
    const float* __restrict__ W1, const float* __restrict__ W2,
    unsigned short* __restrict__ W1b, unsigned short* __restrict__ W2b)
{
    const int bid = blockIdx.x;
    const int tid = threadIdx.x;
    if (bid < 64) {                       // W2 -> bf16 (65536 elems)
        const int i = bid * 1024 + tid * 4;
        const float4 v = *(const float4*)(W2 + i);
        ushort4 o;
        o.x = f2bf(v.x); o.y = f2bf(v.y); o.z = f2bf(v.z); o.w = f2bf(v.w);
        *(ushort4*)(W2b + i) = o;
    } else {                              // W1 -> bf16, 32-col padded rows
        const int i = (bid - 64) * 256 + tid;   // 0..8191
        const int r = i >> 5, c = i & 31;
        W1b[i] = (c < X1Dp) ? f2bf(W1[r * X1Dp + c]) : (unsigned short)0;
    }
}

// ---------------------------------------------------------------------------
// main (fused): 512 blocks x 512 threads (8 waves), 64 positions/block
// = TWO 32-pos tiles of the same batch.
//  - phases A/B: waves 0-3 handle tile 0, waves 4-7 tile 1 (R6 structure
//    per 4-wave group); s4/qk/biases staged ONCE per 64 positions.
//  - phase C: wave w owns 32 output cols, computes ALL 64 rows as 4
//    independent 16-row MFMA chains -> W2b bytes per MFMA HALVED vs R6
//    (64 MB total L2 traffic, was 128 MB), 4-chain ILP (was 2).
//  - W1b B-frags + W2b col-group-0 B-frags pre-issued before phase A
//    (L2 latency hidden under the attention j-loop).
// LDS ~48 KB, grid 512 = 2 blocks/CU, __launch_bounds__(512,2) -> VGPR<=128.
// ---------------------------------------------------------------------------
__global__ __launch_bounds__(512, 2) void main_kernel(
    const float* __restrict__ state, const float* __restrict__ action,
    const float* __restrict__ Wk, const float* __restrict__ Wq,
    const float* __restrict__ Wv,
    const unsigned short* __restrict__ W1b, const unsigned short* __restrict__ W2b,
    const float* __restrict__ b1, const float* __restrict__ b2,
    const float* __restrict__ Wout, const float* __restrict__ bout,
    float* __restrict__ out)
{
    const int bid   = blockIdx.x;        // 0..511
    const int batch = bid >> 1;
    const int t0    = (bid & 1) * 64;
    const int tid   = threadIdx.x;
    const int lane  = tid & 63;
    const int wave  = tid >> 6;          // 0..7
    const int quad  = lane >> 4;
    const int l16   = lane & 15;
    const int tileA = tid >> 8;          // 0/1 (phase A/B tile)
    const int tid8  = tid & 255;
    const int t_loc = tid8 >> 3;         // 0..31
    const int jo    = tid8 & 7;          // 8-way j split
    const int trow  = tileA * 32 + t_loc;   // 0..63 block-local row
    const int t     = t0 + trow;            // batch position

    __shared__ float4 s4[Tp];                                // 2 KB
    __shared__ float  wv[Hp * Kp * Kp];                      // 192 B
    __shared__ float  qk[64 * QKLD];                         // 4.3 KB
    __shared__ float  b1s[HIDp];                             // 1 KB
    __shared__ float  b2s[HIDp];                             // 1 KB
    __shared__ float  wouts[HIDp];                           // 1 KB
    __shared__ __align__(16) unsigned short X1s[64 * 32];    // 4 KB (swizzled)
    __shared__ __align__(16) unsigned short h1s[64 * 256];   // 32 KB (swizzled)
    __shared__ float partial[8][64];                         // 2 KB

    // ---- pre-issue phase-B (W1b) and phase-C col-group-0 (W2b) loads ----
    const int tileB = wave >> 2;         // phase-B tile
    const int rtB   = wave & 1;          // phase-B row-tile
    const int chhB  = (wave >> 1) & 1;   // phase-B col-half
    bf16x8 bfr[8];
    #pragma unroll
    for (int n = 0; n < 8; ++n)
        bfr[n] = *(const bf16x8*)&W1b[(chhB * 128 + n * 16 + l16) * 32 + quad * 8];
    bf16x8 Bc[8];
    {
        const unsigned short* wr0 = W2b + (size_t)(wave * 32 + l16) * HIDp + quad * 8;
        #pragma unroll
        for (int ks = 0; ks < 8; ++ks)
            Bc[ks] = *(const bf16x8*)(wr0 + ks * 32);
    }

    // ---- phase S: parallel staging + per-t precompute (64 t's) ----
    if (tid < Tp) {
        s4[tid] = ((const float4*)(state + (size_t)batch * Tp * SDp))[tid * 2];
    } else if (tid < Tp + 64) {
        const int ta = tid - Tp;            // 0..63
        const int tt = t0 + ta;
        float qs[QDp];
        {
            const float* srow = state + ((size_t)batch * Tp + tt) * SDp;
            const float4 v0 = *(const float4*)srow;
            const float4 v1 = *(const float4*)(srow + 4);
            qs[0]=v0.x; qs[1]=v0.y; qs[2]=v0.z; qs[3]=v0.w;
            qs[4]=v1.x; qs[5]=v1.y; qs[6]=v1.z; qs[7]=v1.w;
            const float* arow = action + ((size_t)batch * Tp + tt) * ADp;
            qs[8] = arow[0]; qs[9] = arow[1];
        }
        float q[Hp * Kp];
        #pragma unroll
        for (int r = 0; r < Hp * Kp; ++r) {
            float a = 0.f;
            #pragma unroll
            for (int d = 0; d < QDp; ++d) a += qs[d] * Wq[r * QDp + d];
            q[r] = a;
        }
        float* qrow = &qk[ta * QKLD];
        #pragma unroll
        for (int h = 0; h < Hp; ++h)
            #pragma unroll
            for (int c = 0; c < Kp; ++c) {
                float a = 0.f;
                #pragma unroll
                for (int k = 0; k < Kp; ++k) a += q[h * Kp + k] * Wk[(h * Kp + k) * Kp + c];
                qrow[h * 4 + c] = 0.5f * LOG2E * a;   // exp->exp2 fold; no max-shift
            }
        #pragma unroll
        for (int i = 0; i < 5; ++i) {
            const unsigned u = (unsigned)f2bf(qs[2*i]) | ((unsigned)f2bf(qs[2*i+1]) << 16);
            qrow[12 + i] = __uint_as_float(u);
        }
    } else if (tid < Tp + 64 + Hp * Kp * Kp) {
        wv[tid - Tp - 64] = Wv[tid - Tp - 64];
    }
    if (tid >= 256) {
        const int i = tid - 256;            // 0..255
        b1s[i]   = b1[i];
        b2s[i]   = b2[i];
        wouts[i] = Wout[i];
    }
    __syncthreads();

    // ---- phase A: j-loop (all 512 threads; 16 j's each) ----
    float rq[12];
    #pragma unroll
    for (int i = 0; i < 3; ++i)
        *(float4*)&rq[i * 4] = *(const float4*)&qk[trow * QKLD + i * 4];

    float l[Hp] = {0.f, 0.f, 0.f};
    float ac[Hp][4] = {};
    #pragma unroll
    for (int i = 0; i < 16; ++i) {
        const int j = (jo << 4) | ((i + jo) & 15);   // rotated: conflict-free banks
        const float4 sj = s4[j];
        #pragma unroll
        for (int h = 0; h < Hp; ++h) {
            const float d = sj.x * rq[h*4] + sj.y * rq[h*4+1]
                          + sj.z * rq[h*4+2] + sj.w * rq[h*4+3];
            const float e = __builtin_amdgcn_exp2f(d);   // no j==t branch
            l[h] += e;
            ac[h][0] += e * sj.x; ac[h][1] += e * sj.y;
            ac[h][2] += e * sj.z; ac[h][3] += e * sj.w;
        }
    }
    #pragma unroll
    for (int off = 1; off < 8; off <<= 1) {
        #pragma unroll
        for (int h = 0; h < Hp; ++h) {
            l[h] += __shfl_xor(l[h], off);
            #pragma unroll
            for (int c = 0; c < Kp; ++c) ac[h][c] += __shfl_xor(ac[h][c], off);
        }
    }

    if (jo == 0) {
        const float4 st = s4[t0 + trow - t0];   // s4[t - batch offset] == s4[trow + t0]? no:
        // NOTE: s4 is indexed by batch position 0..127; t = t0 + trow.
        const float4 stt = s4[t];
        unsigned short rowb[32] __attribute__((aligned(16)));
        #pragma unroll
        for (int h = 0; h < Hp; ++h) {
            // remove the j==t term: e_tt = exp2(dot(qkp_h, s_t))
            const float dtt = stt.x * rq[h*4] + stt.y * rq[h*4+1]
                            + stt.z * rq[h*4+2] + stt.w * rq[h*4+3];
            const float ett = __builtin_amdgcn_exp2f(dtt);
            const float inv = 1.f / (l[h] - ett);
            const float rb0 = (ac[h][0] - ett * stt.x) * inv - stt.x;
            const float rb1 = (ac[h][1] - ett * stt.y) * inv - stt.y;
            const float rb2 = (ac[h][2] - ett * stt.z) * inv - stt.z;
            const float rb3 = (ac[h][3] - ett * stt.w) * inv - stt.w;
            #pragma unroll
            for (int k = 0; k < Kp; ++k) {
                const int r = h * Kp + k;
                rowb[r] = f2bf(rb0 * wv[r*4] + rb1 * wv[r*4+1] + rb2 * wv[r*4+2] + rb3 * wv[r*4+3]);
            }
        }
        #pragma unroll
        for (int i = 0; i < 5; ++i) {
            const unsigned u = __float_as_uint(qk[trow * QKLD + 12 + i]);
            rowb[12 + 2*i] = (unsigned short)(u & 0xffffu);
            rowb[13 + 2*i] = (unsigned short)(u >> 16);
        }
        #pragma unroll
        for (int i = X1Dp; i < 32; ++i) rowb[i] = 0;

        const uint4* srcv = (const uint4*)rowb;
        #pragma unroll
        for (int i = 0; i < 4; ++i)
            *(uint4*)((char*)X1s + x1_byte(trow, i * 16)) = srcv[i];
    }
    __syncthreads();

    // ---- phase B: MLP1 (wave -> tileB, row-tile rtB, col-half chhB) ----
    {
        const bf16x8 afr = *(const bf16x8*)((const char*)X1s +
                             x1_byte(tileB * 32 + rtB * 16 + l16, quad * 16));
        #pragma unroll
        for (int n = 0; n < 8; ++n) {
            const int col = chhB * 128 + n * 16 + l16;
            f32x4 acc = {0.f, 0.f, 0.f, 0.f};
            acc = __builtin_amdgcn_mfma_f32_16x16x32_bf16(afr, bfr[n], acc, 0, 0, 0);
            const float bb = b1s[col];
            #pragma unroll
            for (int r = 0; r < 4; ++r) {
                const int row = tileB * 32 + rtB * 16 + quad * 4 + r;
                *(unsigned short*)((char*)h1s + h1_byte(row, col * 2)) =
                    f2bf(fmaxf(acc[r] + bb, 0.f));
            }
        }
    }
    __syncthreads();

    // ---- phase C: MLP2 + out; wave owns cols [wave*32, wave*32+32),
    //      all 64 rows as 4 independent 16-row MFMA chains ----
    float rsum[4][4] = {};

    // issue col-group-1 B loads NOW (hidden under group-0 MFMAs)
    bf16x8 Bn[8];
    {
        const unsigned short* wr1 = W2b + (size_t)(wave * 32 + 16 + l16) * HIDp + quad * 8;
        #pragma unroll
        for (int ks = 0; ks < 8; ++ks)
            Bn[ks] = *(const bf16x8*)(wr1 + ks * 32);
    }

    #pragma unroll
    for (int i = 0; i < 2; ++i) {
        const int col = wave * 32 + i * 16 + l16;
        const float bb = b2s[col];
        const float wo = wouts[col];
        #pragma unroll
        for (int rt4 = 0; rt4 < 4; ++rt4) {
            f32x4 acc = {0.f, 0.f, 0.f, 0.f};
            #pragma unroll
            for (int ks = 0; ks < 8; ++ks) {
                const bf16x8 a8 = *(const bf16x8*)((const char*)h1s +
                                    h1_byte(rt4 * 16 + l16, ks * 64 + quad * 16));
                acc = __builtin_amdgcn_mfma_f32_16x16x32_bf16(
                          a8, (i == 0) ? Bc[ks] : Bn[ks], acc, 0, 0, 0);
            }
            #pragma unroll
            for (int r = 0; r < 4; ++r)
                rsum[rt4][r] += fmaxf(acc[r] + bb, 0.f) * wo;
        }
    }

    #pragma unroll
    for (int off = 1; off < 16; off <<= 1)
        #pragma unroll
        for (int rt4 = 0; rt4 < 4; ++rt4)
            #pragma unroll
            for (int r = 0; r < 4; ++r)
                rsum[rt4][r] += __shfl_xor(rsum[rt4][r], off);

    if (l16 == 0) {
        #pragma unroll
        for (int rt4 = 0; rt4 < 4; ++rt4)
            #pragma unroll
            for (int r = 0; r < 4; ++r)
                partial[wave][rt4 * 16 + quad * 4 + r] = rsum[rt4][r];
    }
    __syncthreads();

    if (tid < 64) {
        float o = bout[0];
        #pragma unroll
        for (int w = 0; w < 8; ++w) o += partial[w][tid];
        out[(size_t)batch * Tp + t0 + tid] = o;
    }
}

extern "C" void kernel_launch(void* const* d_in, const int* in_sizes, int n_in,
                              void* d_out, int out_size, void* d_ws, size_t ws_size,
                              hipStream_t stream) {
    const float* state  = (const float*)d_in[0];
    const float* action = (const float*)d_in[1];
    const float* Wk     = (const float*)d_in[2];
    const float* Wq     = (const float*)d_in[3];
    const float* Wv     = (const float*)d_in[4];
    const float* W1     = (const float*)d_in[5];
    const float* b1     = (const float*)d_in[6];
    const float* W2     = (const float*)d_in[7];
    const float* b2     = (const float*)d_in[8];
    const float* Wout   = (const float*)d_in[9];
    const float* bout   = (const float*)d_in[10];
    float* out = (float*)d_out;

    char* ws = (char*)d_ws;
    unsigned short* W1b = (unsigned short*)(ws);           // 16 KB
    unsigned short* W2b = (unsigned short*)(ws + 16384);   // 128 KB

    prep_kernel<<<96, 256, 0, stream>>>(W1, W2, W1b, W2b);
    main_kernel<<<2 * Bp, 512, 0, stream>>>(state, action, Wk, Wq, Wv,
                                            W1b, W2b, b1, b2, Wout, bout, out);
}